// Round 2
// baseline (616.574 us; speedup 1.0000x reference)
//
#include <hip/hip_runtime.h>

#define IN_SZ 8192
#define OUT_SZ 8192

// sigmoid(2.0)
#define SIG_TAU 0.8807970779778823f

#define ROWS 64                         // rows per block (split-K chunk)
#define COLS_PER_BLOCK 1024             // 256 threads x float4
#define NUM_RC (IN_SZ / ROWS)           // 128 row chunks
#define NUM_CT (OUT_SZ / COLS_PER_BLOCK) // 8 col tiles

// ---------------------------------------------------------------------------
// Fused streaming kernel: per (col-tile, row-chunk) block
//   - gemv partial: acc[j] += sum_{r in chunk} x[r] * W[r][j]
//   - trace update: Jout[r][j] = sig_tau * J[r][j] + x[r]
// Partials go to ws[rc][j] (no atomics, deterministic).
// Traffic: 768 MB total (read W + read J + write Jout) + 4 MB partials.
// ---------------------------------------------------------------------------
__global__ void fused_kernel(const float* __restrict__ x,
                             const float* __restrict__ J,
                             const float* __restrict__ W,
                             float* __restrict__ Jout,
                             float* __restrict__ partial) {
    __shared__ float xs[ROWS];
    const int tid  = threadIdx.x;
    const int ct   = blockIdx.x;
    const int rc   = blockIdx.y;
    const int col0 = ct * COLS_PER_BLOCK + tid * 4;
    const int row0 = rc * ROWS;

    if (tid < ROWS) xs[tid] = x[row0 + tid];
    __syncthreads();

    const size_t base = (size_t)row0 * OUT_SZ + col0;
    const float* wp = W + base;
    const float* jp = J + base;
    float*       op = Jout + base;

    float4 acc = make_float4(0.f, 0.f, 0.f, 0.f);
#pragma unroll 8
    for (int r = 0; r < ROWS; ++r) {
        const float xi = xs[r];
        float4 w = *(const float4*)wp;
        float4 j = *(const float4*)jp;
        acc.x += xi * w.x;
        acc.y += xi * w.y;
        acc.z += xi * w.z;
        acc.w += xi * w.w;
        float4 o;
        o.x = SIG_TAU * j.x + xi;
        o.y = SIG_TAU * j.y + xi;
        o.z = SIG_TAU * j.z + xi;
        o.w = SIG_TAU * j.w + xi;
        *(float4*)op = o;
        wp += OUT_SZ;
        jp += OUT_SZ;
        op += OUT_SZ;
    }
    *(float4*)(partial + (size_t)rc * OUT_SZ + col0) = acc;
}

// ---------------------------------------------------------------------------
// Finalize: reduce split-K partials, apply LIF update, write u_out and s.
//   I      = sum_rc partial[rc][j]          (4 MB read, coalesced)
//   u_new  = sig_tau*u + I
//   s      = (u_new > 1) ? 1 : 0
//   u_out  = u_new - s
// ---------------------------------------------------------------------------
__global__ void finalize_kernel(const float* __restrict__ u,
                                const float* __restrict__ partial,
                                float* __restrict__ out) {
    const int j = blockIdx.x * blockDim.x + threadIdx.x;
    if (j >= OUT_SZ) return;
    float I = 0.f;
#pragma unroll 8
    for (int rc = 0; rc < NUM_RC; ++rc)
        I += partial[(size_t)rc * OUT_SZ + j];
    float u_new = SIG_TAU * u[j] + I;
    float s     = (u_new > 1.0f) ? 1.0f : 0.0f;
    out[j] = u_new - s;
    out[(size_t)OUT_SZ + (size_t)IN_SZ * OUT_SZ + j] = s;
}

extern "C" void kernel_launch(void* const* d_in, const int* in_sizes, int n_in,
                              void* d_out, int out_size, void* d_ws, size_t ws_size,
                              hipStream_t stream) {
    const float* x = (const float*)d_in[0];   // [IN_SZ]
    const float* u = (const float*)d_in[1];   // [OUT_SZ]
    const float* J = (const float*)d_in[2];   // [IN_SZ, OUT_SZ]
    const float* W = (const float*)d_in[3];   // [IN_SZ, OUT_SZ]
    float* out     = (float*)d_out;
    float* partial = (float*)d_ws;            // [NUM_RC, OUT_SZ] = 4 MB

    fused_kernel<<<dim3(NUM_CT, NUM_RC), 256, 0, stream>>>(x, J, W, out + OUT_SZ, partial);
    finalize_kernel<<<(OUT_SZ + 255) / 256, 256, 0, stream>>>(u, partial, out);
}